// Round 14
// baseline (307.886 us; speedup 1.0000x reference)
//
#include <hip/hip_runtime.h>
#include <stdint.h>

// NeuralMemory (Titans-style) for MI355X / gfx950.
//  norms_only + proj (MFMA skinny GEMM) -> kv GEMM (+half-split kT epilogue) /
//  q GEMM -> mlp_grad (fused MLP fwd/bwd + outer products -> S; no aT/dpT/dxT
//  round-trip) -> scan (folds w+U -> W) -> retrieve (W staged in LDS) ->
//  combine GEMM. Shift-by-63 via natural indexing.
//  GEMM: 128x128 tile, 2-buffer LDS, issue-early global_load_lds, 2 blocks/CU
//  (r12 form; r11 3-buf regressed, r13 counted-vmcnt neutral).

#define SEQ 4096
#define NTOK 8192

typedef unsigned short u16;
typedef __attribute__((ext_vector_type(8))) short short8;
typedef __attribute__((ext_vector_type(4))) float f32x4;
typedef __attribute__((ext_vector_type(2))) unsigned int u32x2;

__device__ __forceinline__ u16 f2b(float f) {
  union { float f; uint32_t u; } c; c.f = f;
  uint32_t u = c.u;
  uint32_t r = (u + 0x7fffu + ((u >> 16) & 1u)) >> 16;
  return (u16)r;
}
__device__ __forceinline__ float b2f(u16 h) {
  union { uint32_t u; float f; } c; c.u = ((uint32_t)h) << 16;
  return c.f;
}
__device__ __forceinline__ float sigm(float x) { return 1.f / (1.f + __expf(-x)); }
__device__ __forceinline__ uint32_t pk2(float a, float b) {
  return (uint32_t)f2b(a) | ((uint32_t)f2b(b) << 16);
}
__device__ __forceinline__ void gl16(const void* g, void* l) {
  __builtin_amdgcn_global_load_lds(
      (const __attribute__((address_space(1))) unsigned int*)g,
      (__attribute__((address_space(3))) unsigned int*)l, 16, 0, 0);
}

// XOR-swizzled element index inside a [rows][128] bf16 tile (16B-granule swizzle)
__device__ __forceinline__ int sidx(int r, int c) {
  return r*128 + ((((c>>3) ^ (r&7))<<3) | (c&7));
}
__device__ __forceinline__ short8 frag_row_lds128(const u16* buf, int row, int ks, int l4) {
  int g = ks*4 + l4;
  return *(const short8*)&buf[row*128 + ((g ^ (row&7))<<3)];
}
// ---- half-split op tiles: [dim:128][k:32], 8-granule XOR swizzle (r2-verified) ----
__device__ __forceinline__ int swzOP(int dim, int k) {
  return dim*32 + ((((k>>3) ^ (dim&3)))<<3) + (k&7);
}
// write 4 consecutive-k bf16 (k0 % 4 == 0) at row dim from 2 packed u32
__device__ __forceinline__ void opw4(u16* tb, int dim, int k0, uint32_t p0, uint32_t p1) {
  u32x2 v; v[0] = p0; v[1] = p1;
  *(u32x2*)&tb[swzOP(dim, k0)] = v;
}
// A/B fragment: row dim, k = l4*8..+7 contiguous
__device__ __forceinline__ short8 opfrag(const u16* tb, int dim, int l4) {
  return *(const short8*)&tb[dim*32 + ((l4 ^ (dim&3))<<3)];
}

// ---------------- weight prep ----------------

__global__ __launch_bounds__(256) void transpose_bf16(
    const float* __restrict__ src, u16* __restrict__ dst, int R, int C)
{
  __shared__ u16 tile[64*66];
  int tiles_x = C >> 6;
  int tx = blockIdx.x % tiles_x, ty = blockIdx.x / tiles_x;
  int c0 = tx*64, r0 = ty*64;
#pragma unroll
  for (int it=0; it<16; ++it) {
    int idx = it*256 + threadIdx.x;
    int rr = idx>>6, cc = idx&63;
    tile[cc*66 + rr] = f2b(src[(size_t)(r0+rr)*C + c0+cc]);
  }
  __syncthreads();
#pragma unroll
  for (int it=0; it<16; ++it) {
    int idx = it*256 + threadIdx.x;
    int rr = idx>>6, cc = idx&63;
    dst[(size_t)(c0+rr)*R + r0+cc] = tile[rr*66 + cc];
  }
}

__global__ __launch_bounds__(256) void smallprep(
    const float* __restrict__ w0, const float* __restrict__ w1,
    u16* __restrict__ w0Ts, u16* __restrict__ w1Ts, u16* __restrict__ w1bs)
{
  int id = blockIdx.x*256 + threadIdx.x;   // 0..16383
  int i = id>>7, j = id&127;
  float a = w0[id], b = w1[id];
  w0Ts[sidx(j,i)] = f2b(a);
  w1Ts[sidx(j,i)] = f2b(b);
  w1bs[sidx(i,j)] = f2b(b);
}

// Bt16[16][1024]: rows 0-7 = wstep^T, rows 8-15 = wgate^T (bf16)
__global__ __launch_bounds__(256) void proj_prep(
    const float* __restrict__ wstep, const float* __restrict__ wgatew,
    u16* __restrict__ Bt16)
{
  int id = blockIdx.x*256 + threadIdx.x;   // 0..16383
  int n = id>>10, k = id&1023;
  float v = (n < 8) ? wstep[k*8 + n] : wgatew[k*8 + (n-8)];
  Bt16[id] = f2b(v);
}

// ---------------- norms: streaming rmsnorm, one wave per token ----------------

__global__ __launch_bounds__(256) void norms_only(
    const float* __restrict__ seq, const float* __restrict__ gs,
    const float* __restrict__ gr, u16* __restrict__ ss, u16* __restrict__ sr)
{
  int w = threadIdx.x>>6, lane = threadIdx.x&63;
  int t = blockIdx.x*4 + w;
  const float* row = seq + (size_t)t*1024;
  f32x4 x[4];
  float ssq = 0.f;
#pragma unroll
  for (int j=0;j<4;++j) {
    x[j] = *(const f32x4*)&row[j*256 + lane*4];
    ssq += x[j][0]*x[j][0] + x[j][1]*x[j][1] + x[j][2]*x[j][2] + x[j][3]*x[j][3];
  }
  for (int m=32;m;m>>=1) ssq += __shfl_xor(ssq, m);
  float inv = rsqrtf(ssq*(1.f/1024.f) + 1e-6f);
#pragma unroll
  for (int j=0;j<4;++j) {
    int d = j*256 + lane*4;
    f32x4 g4 = *(const f32x4*)&gs[d];
    f32x4 r4 = *(const f32x4*)&gr[d];
    u32x2 ps, pr;
    ps[0] = pk2(x[j][0]*inv*g4[0], x[j][1]*inv*g4[1]);
    ps[1] = pk2(x[j][2]*inv*g4[2], x[j][3]*inv*g4[3]);
    pr[0] = pk2(x[j][0]*inv*r4[0], x[j][1]*inv*r4[1]);
    pr[1] = pk2(x[j][2]*inv*r4[2], x[j][3]*inv*r4[3]);
    *(u32x2*)&ss[(size_t)t*1024 + d] = ps;
    *(u32x2*)&sr[(size_t)t*1024 + d] = pr;
  }
}

// ---------------- proj: lr/gate via MFMA skinny GEMM ----------------

__global__ __launch_bounds__(64) void proj_kernel(
    const u16* __restrict__ ss, const u16* __restrict__ sr,
    const u16* __restrict__ Bt16, float* __restrict__ lr,
    float* __restrict__ gate)
{
  int lane = threadIdx.x;
  int l15 = lane&15, l4 = lane>>4;
  size_t t0 = (size_t)blockIdx.x*16;
  f32x4 acc1 = {}, acc2 = {};
#pragma unroll 8
  for (int ks=0; ks<32; ++ks) {
    int kof = ks*32 + l4*8;
    short8 bf = *(const short8*)&Bt16[l15*1024 + kof];
    short8 as = *(const short8*)&ss[(t0+l15)*1024 + kof];
    short8 ar = *(const short8*)&sr[(t0+l15)*1024 + kof];
    acc1 = __builtin_amdgcn_mfma_f32_16x16x32_bf16(as, bf, acc1, 0,0,0);
    acc2 = __builtin_amdgcn_mfma_f32_16x16x32_bf16(ar, bf, acc2, 0,0,0);
  }
  int col = l15;
#pragma unroll
  for (int j=0;j<4;++j) {
    int t = (int)t0 + l4*4 + j;
    int b = t>>12, pos = t&4095;
    if (col < 8) lr[((size_t)(b*8+col))*4096 + pos] = sigm(acc1[j])*0.01f;
    else gate[((size_t)(b*8+(col-8)))*4096 + pos] = sigm(acc2[j]);
  }
}

// ---------------- per-chunk gates from cmean (vectorized loads) ----------------

__global__ __launch_bounds__(256) void chunkgates_kernel(
    const u16* __restrict__ ss, const float* __restrict__ wmom,
    const float* __restrict__ wdec, float* __restrict__ mg,
    float* __restrict__ d1m)
{
  int bc = blockIdx.x; int b = bc>>6, ch = bc&63;
  size_t t0 = (size_t)(b*4096 + ch*64)*1024;
  int tid = threadIdx.x;
  int d0 = tid*4;                       // 4 contiguous cols per thread
  float cm[4]; cm[0]=cm[1]=cm[2]=cm[3]=0.f;
  for (int tok=0; tok<64; ++tok) {
    u32x2 v2 = *(const u32x2*)&ss[t0 + (size_t)tok*1024 + d0];
    cm[0] += b2f((u16)(v2[0] & 0xffffu));
    cm[1] += b2f((u16)(v2[0] >> 16));
    cm[2] += b2f((u16)(v2[1] & 0xffffu));
    cm[3] += b2f((u16)(v2[1] >> 16));
  }
  float pm[8], pd[8];
#pragma unroll
  for (int h=0;h<8;++h){ pm[h]=0.f; pd[h]=0.f; }
#pragma unroll
  for (int i=0;i<4;++i) {
    float v = cm[i]*(1.f/64.f);
    int d = d0 + i;
#pragma unroll
    for (int h=0;h<8;++h){ pm[h]+=v*wmom[d*8+h]; pd[h]+=v*wdec[d*8+h]; }
  }
#pragma unroll
  for (int h=0;h<8;++h)
    for (int m=32;m;m>>=1){ pm[h] += __shfl_xor(pm[h],m); pd[h] += __shfl_xor(pd[h],m); }
  __shared__ float r2[4][16];
  int wv = tid>>6;
  if ((tid&63)==0) {
#pragma unroll
    for (int h=0;h<8;++h){ r2[wv][h]=pm[h]; r2[wv][8+h]=pd[h]; }
  }
  __syncthreads();
  if (tid < 16) {
    float s = r2[0][tid]+r2[1][tid]+r2[2][tid]+r2[3][tid];
    if (tid<8) mg[(b*8+tid)*64 + ch] = sigm(s);
    else d1m[(b*8+(tid-8))*64 + ch] = 1.f - sigm(s);
  }
}

// ---------------- generic bf16 GEMM: C = A(MxK) @ Bt(NxK)^T ----------------
// 512 threads, 8 waves (2M x 4N), wave tile 64x32, double-buffered LDS (64KB),
// issue-early staging: STAGE(next) -> ds_read+MFMA(cur) -> vmcnt(0)+barrier.
// kvT != nullptr (kv GEMM only): keys half (col<1024) additionally stored as
// per-chunk HALF-SPLIT transposed tiles kT[chunk][half:2][d:128][r:32] (swzOP).

__global__ __launch_bounds__(512, 4) void gemm_bt(
    const u16* __restrict__ A, const u16* __restrict__ Bt,
    void* __restrict__ C, int M, int N, int K, int out_f32,
    u16* __restrict__ kvT)
{
  __shared__ __align__(16) u16 As[2][128*64];
  __shared__ __align__(16) u16 Bs[2][128*64];
  int tid = threadIdx.x;
  int w = tid>>6, lane = tid&63;
  int wr = w>>2, wc = w&3;
  int l15 = lane&15, l4 = lane>>4;
  int rl = lane>>3;
  int cg = (lane&7) ^ rl;
  int nwg = gridDim.x*gridDim.y;
  int wg  = blockIdx.y*gridDim.x + blockIdx.x;
  int cpx = nwg >> 3;
  int swz = (wg & 7)*cpx + (wg >> 3);
  int bx = swz % gridDim.x, by = swz / gridDim.x;
  int brow = by*128, bcol = bx*128;
  f32x4 acc[4][2] = {};

  auto STAGE = [&](int buf, int kt) {
#pragma unroll
    for (int i=0;i<2;++i) {
      int row = w*16 + i*8;
      gl16(&A [(size_t)(brow+row+rl)*K + kt + cg*8], &As[buf][row*64]);
      gl16(&Bt[(size_t)(bcol+row+rl)*K + kt + cg*8], &Bs[buf][row*64]);
    }
  };

  int nk = K >> 6;
  STAGE(0, 0);
  asm volatile("s_waitcnt vmcnt(0)");
  __syncthreads();
  for (int t=0; t<nk; ++t) {
    int cur = t & 1;
    if (t+1 < nk) STAGE(cur^1, (t+1)*64);
#pragma unroll
    for (int ks=0; ks<2; ++ks) {
      short8 af[4], bf[2];
#pragma unroll
      for (int m=0;m<4;++m) {
        int row = wr*64 + m*16 + l15;
        int g = ks*4 + l4;
        af[m] = *(const short8*)&As[cur][row*64 + ((g ^ (row&7))<<3)];
      }
#pragma unroll
      for (int n=0;n<2;++n) {
        int row = wc*32 + n*16 + l15;
        int g = ks*4 + l4;
        bf[n] = *(const short8*)&Bs[cur][row*64 + ((g ^ (row&7))<<3)];
      }
#pragma unroll
      for (int m=0;m<4;++m)
#pragma unroll
        for (int n=0;n<2;++n)
          acc[m][n] = __builtin_amdgcn_mfma_f32_16x16x32_bf16(af[m], bf[n], acc[m][n], 0,0,0);
    }
    asm volatile("s_waitcnt vmcnt(0)");
    __syncthreads();
  }
#pragma unroll
  for (int m=0;m<4;++m) {
#pragma unroll
    for (int n=0;n<2;++n) {
      int col = bcol + wc*32 + n*16 + l15;
#pragma unroll
      for (int j=0;j<4;++j) {
        int row = brow + wr*64 + m*16 + l4*4 + j;
        if (out_f32) ((float*)C)[(size_t)row*N + col] = acc[m][n][j];
        else ((u16*)C)[(size_t)row*N + col] = f2b(acc[m][n][j]);
      }
    }
  }
  if (kvT) {
#pragma unroll
    for (int m=0;m<4;++m) {
#pragma unroll
      for (int n=0;n<2;++n) {
        int col = bcol + wc*32 + n*16 + l15;
        if (col < 1024) {
          int row0 = brow + wr*64 + m*16 + l4*4;
          int d = col & 127;
          int chunk = ((row0>>12)*8 + (col>>7))*64 + ((row0&4095)>>6);
          int rr = row0 & 63;
          int hf = rr >> 5, r5 = rr & 31;
          u32x2 p; p[0] = pk2(acc[m][n][0], acc[m][n][1]);
                   p[1] = pk2(acc[m][n][2], acc[m][n][3]);
          *(u32x2*)&kvT[(size_t)chunk*8192 + hf*4096 + swzOP(d, r5)] = p;
        }
      }
    }
  }
}

// ---------------- mlp_grad: fused MLP fwd/bwd + outer products -> S ----------------
// 8 waves; waves 0-3 own chunk (blk*4+it2*2), waves 4-7 own +1; each wave = 16 rows.
// After dx: build half-split op tiles in abuf (dead scratch) and MFMA the outer
// products with the same 4 waves; S written directly (sidx layout, unchanged).

__global__ __launch_bounds__(512) void mlp_grad(
    const u16* __restrict__ kvout, const float* __restrict__ lr,
    const u16* __restrict__ w0Ts, const u16* __restrict__ w1Ts,
    const u16* __restrict__ w1bs, const u16* __restrict__ kTg,
    u16* __restrict__ S)
{
  __shared__ __align__(16) u16 W0L[16384];
  __shared__ __align__(16) u16 W1L[16384];
  __shared__ __align__(16) u16 WBL[16384];
  __shared__ __align__(16) u16 abuf[16384];   // mlp scratch, then op tiles
  int tid = threadIdx.x;
  int w = tid>>6, lane = tid&63;
  int l15 = lane&15, l4 = lane>>4;
#pragma unroll
  for (int it=0; it<4; ++it) {
    int wb = it*512 + w*64;
    gl16((const short8*)w0Ts + wb + lane, (short8*)W0L + wb);
    gl16((const short8*)w1Ts + wb + lane, (short8*)W1L + wb);
    gl16((const short8*)w1bs + wb + lane, (short8*)WBL + wb);
  }
  __syncthreads();
  u16* ab = abuf + w*2048;          // per-wave [16][128] slice
  int r0 = l4*4;
  int q4 = w&3, half = w>>2;
  int rb = q4*16;
  int k0 = (q4&1)*16 + r0;          // k-position within the wave's r-half
  u16* ob = abuf + half*8192;       // group op tiles: A [0..4095], B [4096..8191]

  for (int it2=0; it2<2; ++it2) {
    int cidx = blockIdx.x*4 + it2*2 + half;
    int bh = cidx>>6, ch = cidx&63;
    int b = bh>>3, hh = bh&7;
    size_t t0 = (size_t)(b*4096 + ch*64 + rb);
    f32x4 lrv = *(const f32x4*)&lr[(size_t)bh*4096 + ch*64 + rb + r0];

    // x1 = k @ w0 (A-frags direct global; B from LDS)
    f32x4 x1[8] = {};
#pragma unroll
    for (int ks=0; ks<4; ++ks) {
      short8 af = *(const short8*)&kvout[(t0 + l15)*2048 + hh*128 + ks*32 + l4*8];
#pragma unroll
      for (int n=0;n<8;++n) {
        short8 bf = frag_row_lds128(W0L, n*16+l15, ks, l4);
        x1[n] = __builtin_amdgcn_mfma_f32_16x16x32_bf16(af, bf, x1[n], 0,0,0);
      }
    }
    // a = silu(x1): own LDS rows + packed regs
    uint32_t a_pk[16];
#pragma unroll
    for (int n=0;n<8;++n) {
      int c = n*16 + l15;
      float av[4];
#pragma unroll
      for (int j=0;j<4;++j){ float xv = x1[n][j]; av[j] = xv*sigm(xv); }
      ab[sidx(r0+0,c)] = f2b(av[0]);
      ab[sidx(r0+1,c)] = f2b(av[1]);
      ab[sidx(r0+2,c)] = f2b(av[2]);
      ab[sidx(r0+3,c)] = f2b(av[3]);
      a_pk[n*2]   = pk2(av[0],av[1]);
      a_pk[n*2+1] = pk2(av[2],av[3]);
    }
    // pred = a @ w1
    f32x4 pr[8] = {};
#pragma unroll
    for (int ks=0; ks<4; ++ks) {
      short8 af = frag_row_lds128(ab, l15, ks, l4);
#pragma unroll
      for (int n=0;n<8;++n) {
        short8 bf = frag_row_lds128(W1L, n*16+l15, ks, l4);
        pr[n] = __builtin_amdgcn_mfma_f32_16x16x32_bf16(af, bf, pr[n], 0,0,0);
      }
    }
    // dpred = (2/128)*lr*(pred - v)
    uint32_t dp_pk[16];
#pragma unroll
    for (int n=0;n<8;++n) {
      int c = n*16 + l15;
      float dv[4];
#pragma unroll
      for (int j=0;j<4;++j) {
        float vv = b2f(kvout[(t0+r0+j)*2048 + 1024 + hh*128 + c]);
        dv[j] = 0.015625f * lrv[j] * (pr[n][j] - vv);
      }
      ab[sidx(r0+0,c)] = f2b(dv[0]);
      ab[sidx(r0+1,c)] = f2b(dv[1]);
      ab[sidx(r0+2,c)] = f2b(dv[2]);
      ab[sidx(r0+3,c)] = f2b(dv[3]);
      dp_pk[n*2]   = pk2(dv[0],dv[1]);
      dp_pk[n*2+1] = pk2(dv[2],dv[3]);
    }
    // da = dpred @ w1^T
    f32x4 da[8] = {};
#pragma unroll
    for (int ks=0; ks<4; ++ks) {
      short8 af = frag_row_lds128(ab, l15, ks, l4);
#pragma unroll
      for (int n=0;n<8;++n) {
        short8 bf = frag_row_lds128(WBL, n*16+l15, ks, l4);
        da[n] = __builtin_amdgcn_mfma_f32_16x16x32_bf16(af, bf, da[n], 0,0,0);
      }
    }
    // dx1 = da * silu'(x1) -> packed regs only
    uint32_t dx_pk[16];
#pragma unroll
    for (int n=0;n<8;++n) {
      float d[4];
#pragma unroll
      for (int j=0;j<4;++j) {
        float xv = x1[n][j];
        float sg = sigm(xv);
        d[j] = da[n][j]*(sg*(1.f + xv*(1.f - sg)));
      }
      dx_pk[n*2]   = pk2(d[0],d[1]);
      dx_pk[n*2+1] = pk2(d[2],d[3]);
    }

    // ---- outer products (group-local, block-wide symmetric barriers) ----
    // S1T[eo][em] = -sum_r dp[r][eo] a[r][em]
    f32x4 g1[2][8] = {};
#pragma unroll
    for (int hf=0; hf<2; ++hf) {
      __syncthreads();                          // ab scratch / prev MFMA done
      if ((q4>>1) == hf) {
#pragma unroll
        for (int n=0;n<8;++n) {
          int c = n*16 + l15;
          opw4(ob,      c, k0, dp_pk[n*2], dp_pk[n*2+1]);
          opw4(ob+4096, c, k0, a_pk[n*2],  a_pk[n*2+1]);
        }
      }
      __syncthreads();
#pragma unroll
      for (int n=0;n<8;++n) {
        short8 bf = opfrag(ob+4096, n*16 + l15, l4);
#pragma unroll
        for (int mi=0;mi<2;++mi) {
          short8 af = opfrag(ob, q4*32 + mi*16 + l15, l4);
          g1[mi][n] = __builtin_amdgcn_mfma_f32_16x16x32_bf16(af, bf, g1[mi][n], 0,0,0);
        }
      }
    }
    {
      u16* S1 = S + ((size_t)(16+bh)*64 + ch)*16384;
#pragma unroll
      for (int mi=0;mi<2;++mi)
#pragma unroll
        for (int n=0;n<8;++n)
#pragma unroll
          for (int j=0;j<4;++j) {
            int m = q4*32 + mi*16 + l4*4 + j, c = n*16 + l15;
            S1[sidx(m,c)] = f2b(-g1[mi][n][j]);
          }
    }
    // S0T[em][ei] = -sum_r dx[r][em] k[r][ei]  (kT halves from global, swzOP)
    f32x4 g0[2][8] = {};
    const u16* kts = kTg + (size_t)cidx*8192;
#pragma unroll
    for (int hf=0; hf<2; ++hf) {
      __syncthreads();                          // prev MFMA done reading ob
      if ((q4>>1) == hf) {
#pragma unroll
        for (int n=0;n<8;++n)
          opw4(ob, n*16 + l15, k0, dx_pk[n*2], dx_pk[n*2+1]);
      }
#pragma unroll
      for (int it=0; it<2; ++it) {
        int off = it*2048 + q4*512;             // u16 units, wave-uniform
        gl16(kts + hf*4096 + off + lane*8, ob + 4096 + off);
      }
      __syncthreads();
#pragma unroll
      for (int n=0;n<8;++n) {
        short8 bf = opfrag(ob+4096, n*16 + l15, l4);
#pragma unroll
        for (int mi=0;mi<2;++mi) {
          short8 af = opfrag(ob, q4*32 + mi*16 + l15, l4);
          g0[mi][n] = __builtin_amdgcn_mfma_f32_16x16x32_bf16(af, bf, g0[mi][n], 0,0,0);
        }
      }
    }
    {
      u16* S0 = S + ((size_t)bh*64 + ch)*16384;
#pragma unroll
      for (int mi=0;mi<2;++mi)
#pragma unroll
        for (int n=0;n<8;++n)
#pragma unroll
          for (int j=0;j<4;++j) {
            int m = q4*32 + mi*16 + l4*4 + j, c = n*16 + l15;
            S0[sidx(m,c)] = f2b(-g0[mi][n][j]);
          }
    }
    __syncthreads();                            // ob dead before next it2 ab use
  }
}

// ---- scan: double linear recurrence, 2 elements/thread (u32 packed) ----

__global__ __launch_bounds__(256) void scan_kernel(
    u16* __restrict__ S, const float* __restrict__ mg, const float* __restrict__ d1m,
    const u16* __restrict__ w0Ts, const u16* __restrict__ w1Ts)
{
  int bidx = blockIdx.x;              // mbh*32 + eblk
  int eblk = bidx & 31;
  int mbh = bidx >> 5;                // 0..31 (0..15 = S0/w0, 16..31 = S1/w1)
  int bh = mbh & 15;
  int e = (eblk*256 + threadIdx.x)*2;
  uint32_t* base = (uint32_t*)(S + (size_t)mbh*64*16384 + e);
  const u16* wsrc = (mbh < 16) ? w0Ts : w1Ts;
  uint32_t wp = *(const uint32_t*)&wsrc[e];
  float wv0 = b2f((u16)(wp & 0xffffu)), wv1 = b2f((u16)(wp >> 16));
  const float* g1 = mg + bh*64;
  const float* g2 = d1m + bh*64;
  float mom0=0.f, upd0=0.f, mom1=0.f, upd1=0.f;
  for (int c2=0; c2<64; ++c2) {
    uint32_t s2 = base[(size_t)c2*8192];
    float s0 = b2f((u16)(s2 & 0xffffu)), s1 = b2f((u16)(s2 >> 16));
    float gg1 = g1[c2], gg2 = g2[c2];
    mom0 = gg1*mom0 + s0; upd0 = gg2*upd0 + mom0;
    mom1 = gg1*mom1 + s1; upd1 = gg2*upd1 + mom1;
    base[(size_t)c2*8192] = pk2(wv0 + upd0, wv1 + upd1);
  }
}

// ---------------- retrieval ----------------

__global__ __launch_bounds__(256) void retrieve_kernel(
    const u16* __restrict__ qn, const u16* __restrict__ W,
    const float* __restrict__ gamma, const float* __restrict__ gate,
    u16* __restrict__ vals)
{
  __shared__ __align__(16) u16 W0s[16384];
  __shared__ __align__(16) u16 W1s[16384];
  __shared__ __align__(16) u16 QA[8192];
  int bid = blockIdx.x;
  int bh = bid>>6, ch = bid&63;
  int b = bh>>3, h = bh&7;
  int tid = threadIdx.x;
  int w = tid>>6, lane = tid&63;
  int l15 = lane&15, l4 = lane>>4;
  const u16* W0g = W + ((size_t)bh*64 + ch)*16384;
  const u16* W1g = W + ((size_t)(16+bh)*64 + ch)*16384;
#pragma unroll
  for (int it=0; it<8; ++it) {
    int wb = it*256 + w*64;
    gl16((const short8*)W0g + wb + lane, (short8*)W0s + wb);
    gl16((const short8*)W1g + wb + lane, (short8*)W1s + wb);
  }
  u16* qa = QA + w*2048;
#pragma unroll
  for (int it=0; it<4; ++it) {
    int task = it*64 + lane;
    int rloc = task>>4, g = task&15;
    int posn = ch*64 + w*16 + rloc + 63;
    short8 v;
    if (posn < 4096) v = *(const short8*)&qn[((size_t)(b*4096+posn))*1024 + h*128 + g*8];
    else {
#pragma unroll
      for (int i=0;i<8;++i) v[i]=0;
    }
    *(short8*)&qa[rloc*128 + ((g ^ (rloc&7))<<3)] = v;
  }
  __syncthreads();
  f32x4 xx[8] = {};
#pragma unroll
  for (int ks=0; ks<4; ++ks) {
    short8 af = frag_row_lds128(qa, l15, ks, l4);
#pragma unroll
    for (int n=0;n<8;++n) {
      short8 bf = frag_row_lds128(W0s, n*16+l15, ks, l4);
      xx[n] = __builtin_amdgcn_mfma_f32_16x16x32_bf16(af, bf, xx[n], 0,0,0);
    }
  }
  int r0 = l4*4;
#pragma unroll
  for (int n=0;n<8;++n) {
    int c = n*16 + l15;
#pragma unroll
    for (int j=0;j<4;++j) {
      float xv = xx[n][j];
      qa[sidx(r0+j,c)] = f2b(xv * sigm(xv));
    }
  }
  f32x4 vv[8] = {};
#pragma unroll
  for (int ks=0; ks<4; ++ks) {
    short8 af = frag_row_lds128(qa, l15, ks, l4);
#pragma unroll
    for (int n=0;n<8;++n) {
      short8 bf = frag_row_lds128(W1s, n*16+l15, ks, l4);
      vv[n] = __builtin_amdgcn_mfma_f32_16x16x32_bf16(af, bf, vv[n], 0,0,0);
    }
  }
#pragma unroll
  for (int j=0;j<4;++j) {
    float ssq = 0.f;
#pragma unroll
    for (int n=0;n<8;++n) ssq += vv[n][j]*vv[n][j];
    ssq += __shfl_xor(ssq,1); ssq += __shfl_xor(ssq,2);
    ssq += __shfl_xor(ssq,4); ssq += __shfl_xor(ssq,8);
    float rms = rsqrtf(ssq*(1.f/128.f) + 1e-6f);
    int posn = ch*64 + w*16 + r0 + j + 63;
    if (posn < 4096) {
      float gt = gate[(size_t)bh*4096 + posn];
      size_t orow = ((size_t)(b*4096+posn))*1024 + h*128;
#pragma unroll
      for (int n=0;n<8;++n) {
        int c = n*16 + l15;
        vals[orow + c] = f2b(vv[n][j]*rms*(1.f + gamma[h*128+c])*gt);
      }
    }
  }
}

extern "C" void kernel_launch(void* const* d_in, const int* in_sizes, int n_in,
                              void* d_out, int out_size, void* d_ws, size_t ws_size,
                              hipStream_t stream) {
  const float* seq    = (const float*)d_in[0];
  const float* gstore = (const float*)d_in[1];
  const float* gret   = (const float*)d_in[2];
  const float* wkv    = (const float*)d_in[3];
  const float* wq     = (const float*)d_in[4];
  const float* wstep  = (const float*)d_in[5];
  const float* wmom   = (const float*)d_in[6];
  const float* wdec   = (const float*)d_in[7];
  const float* wgatew = (const float*)d_in[8];
  const float* wcomb  = (const float*)d_in[9];
  const float* gamma  = (const float*)d_in[10];
  const float* w0f    = (const float*)d_in[11];
  const float* w1f    = (const float*)d_in[12];
  float* out = (float*)d_out;
  (void)in_sizes; (void)n_in; (void)out_size; (void)ws_size;

  char* p = (char*)d_ws;
  size_t off = 0;
  auto alloc = [&](size_t bytes) -> void* {
    void* r = p + off; off += (bytes + 255) & ~(size_t)255; return r;
  };
  u16* wkvT   = (u16*)alloc((size_t)2048*1024*2);
  u16* wqT    = (u16*)alloc((size_t)1024*1024*2);
  u16* wcombT = (u16*)alloc((size_t)1024*1024*2);
  u16* w0Ts   = (u16*)alloc(16384*2);
  u16* w1Ts   = (u16*)alloc(16384*2);
  u16* w1bs   = (u16*)alloc(16384*2);
  u16* Bt16   = (u16*)alloc(16384*2);
  u16* ss     = (u16*)alloc((size_t)NTOK*1024*2);
  u16* sr     = (u16*)alloc((size_t)NTOK*1024*2);
  u16* kvout  = (u16*)alloc((size_t)NTOK*2048*2);
  u16* qn     = (u16*)alloc((size_t)NTOK*1024*2);
  u16* vals   = (u16*)alloc((size_t)NTOK*1024*2);
  float* lr   = (float*)alloc((size_t)16*4096*4);
  float* gate = (float*)alloc((size_t)16*4096*4);
  float* mg   = (float*)alloc(1024*4);
  float* d1m  = (float*)alloc(1024*4);
  u16* S      = (u16*)alloc((size_t)32*64*16384*2);
  u16* kTg    = (u16*)alloc((size_t)1024*8192*2);

  transpose_bf16<<<dim3(512),dim3(256),0,stream>>>(wkv, wkvT, 1024, 2048);
  transpose_bf16<<<dim3(256),dim3(256),0,stream>>>(wq, wqT, 1024, 1024);
  transpose_bf16<<<dim3(256),dim3(256),0,stream>>>(wcomb, wcombT, 1024, 1024);
  smallprep<<<dim3(64),dim3(256),0,stream>>>(w0f, w1f, w0Ts, w1Ts, w1bs);
  proj_prep<<<dim3(64),dim3(256),0,stream>>>(wstep, wgatew, Bt16);
  norms_only<<<dim3(2048),dim3(256),0,stream>>>(seq, gstore, gret, ss, sr);
  proj_kernel<<<dim3(512),dim3(64),0,stream>>>(ss, sr, Bt16, lr, gate);
  chunkgates_kernel<<<dim3(128),dim3(256),0,stream>>>(ss, wmom, wdec, mg, d1m);
  gemm_bt<<<dim3(16,64),dim3(512),0,stream>>>(ss, wkvT, kvout, 8192, 2048, 1024, 0, kTg);
  gemm_bt<<<dim3(8,64),dim3(512),0,stream>>>(sr, wqT, qn, 8192, 1024, 1024, 0, nullptr);
  mlp_grad<<<dim3(256),dim3(512),0,stream>>>(kvout, lr, w0Ts, w1Ts, w1bs, kTg, S);
  scan_kernel<<<dim3(1024),dim3(256),0,stream>>>(S, mg, d1m, w0Ts, w1Ts);
  hipMemsetAsync(vals, 0, 63*1024*2, stream);
  hipMemsetAsync(vals + (size_t)4096*1024, 0, 63*1024*2, stream);
  retrieve_kernel<<<dim3(1024),dim3(256),0,stream>>>(qn, S, gamma, gate, vals);
  gemm_bt<<<dim3(8,64),dim3(512),0,stream>>>(vals, wcombT, out, 8192, 1024, 1024, 1, nullptr);
}

// Round 15
// 239.463 us; speedup vs baseline: 1.2857x; 1.2857x over previous
//
#include <hip/hip_runtime.h>
#include <stdint.h>

// NeuralMemory (Titans-style) for MI355X / gfx950.
//  norms_only (streaming rmsnorm) + proj (MFMA skinny GEMM -> lr/gate) ->
//  kv GEMM (+kT epilogue) / q GEMM -> mlp_fwd (weights in LDS) ->
//  grad_op (outer products -> S, swizzled) -> scan (folds w+U -> W, x2 vec) ->
//  retrieve (W staged in LDS) -> combine GEMM. Shift-by-63 via natural indexing.
//  GEMM: 128x128 tile, 2-buffer LDS, issue-early global_load_lds, 2 blocks/CU.
//  [History: r11 3-buf (-50us, FETCH x2, 1 blk/CU); r13 counted-vmcnt neutral;
//   r14 mlp+grad fusion (-70us: 2B scatter S stores 193MB WRITE, 1 blk/CU,
//   bank conflicts). This is the r12 measured-best + vectorized chunkgates.]

#define SEQ 4096
#define NTOK 8192

typedef unsigned short u16;
typedef __attribute__((ext_vector_type(8))) short short8;
typedef __attribute__((ext_vector_type(4))) float f32x4;
typedef __attribute__((ext_vector_type(2))) unsigned int u32x2;

__device__ __forceinline__ u16 f2b(float f) {
  union { float f; uint32_t u; } c; c.f = f;
  uint32_t u = c.u;
  uint32_t r = (u + 0x7fffu + ((u >> 16) & 1u)) >> 16;
  return (u16)r;
}
__device__ __forceinline__ float b2f(u16 h) {
  union { uint32_t u; float f; } c; c.u = ((uint32_t)h) << 16;
  return c.f;
}
__device__ __forceinline__ float sigm(float x) { return 1.f / (1.f + __expf(-x)); }
__device__ __forceinline__ uint32_t pk2(float a, float b) {
  return (uint32_t)f2b(a) | ((uint32_t)f2b(b) << 16);
}
__device__ __forceinline__ void gl16(const void* g, void* l) {
  __builtin_amdgcn_global_load_lds(
      (const __attribute__((address_space(1))) unsigned int*)g,
      (__attribute__((address_space(3))) unsigned int*)l, 16, 0, 0);
}

__device__ __forceinline__ int sidx(int r, int c) {
  return r*128 + ((((c>>3) ^ (r&7))<<3) | (c&7));
}
__device__ __forceinline__ short8 frag_row_lds128(const u16* buf, int row, int ks, int l4) {
  int g = ks*4 + l4;
  return *(const short8*)&buf[row*128 + ((g ^ (row&7))<<3)];
}
__device__ __forceinline__ short8 frag_tile(const u16* t, int row, int ks, int l4) {
  return *(const short8*)&t[row*64 + (((ks*4 + l4) ^ (row&7))<<3)];
}
__device__ __forceinline__ int taddr(int c, int r0) {
  return c*64 + (r0 ^ ((c&7)<<3));
}

// ---------------- weight prep ----------------

__global__ __launch_bounds__(256) void transpose_bf16(
    const float* __restrict__ src, u16* __restrict__ dst, int R, int C)
{
  __shared__ u16 tile[64*66];
  int tiles_x = C >> 6;
  int tx = blockIdx.x % tiles_x, ty = blockIdx.x / tiles_x;
  int c0 = tx*64, r0 = ty*64;
#pragma unroll
  for (int it=0; it<16; ++it) {
    int idx = it*256 + threadIdx.x;
    int rr = idx>>6, cc = idx&63;
    tile[cc*66 + rr] = f2b(src[(size_t)(r0+rr)*C + c0+cc]);
  }
  __syncthreads();
#pragma unroll
  for (int it=0; it<16; ++it) {
    int idx = it*256 + threadIdx.x;
    int rr = idx>>6, cc = idx&63;
    dst[(size_t)(c0+rr)*R + r0+cc] = tile[rr*66 + cc];
  }
}

__global__ __launch_bounds__(256) void smallprep(
    const float* __restrict__ w0, const float* __restrict__ w1,
    u16* __restrict__ w0Ts, u16* __restrict__ w1Ts, u16* __restrict__ w1bs)
{
  int id = blockIdx.x*256 + threadIdx.x;   // 0..16383
  int i = id>>7, j = id&127;
  float a = w0[id], b = w1[id];
  w0Ts[sidx(j,i)] = f2b(a);
  w1Ts[sidx(j,i)] = f2b(b);
  w1bs[sidx(i,j)] = f2b(b);
}

// Bt16[16][1024]: rows 0-7 = wstep^T, rows 8-15 = wgate^T (bf16)
__global__ __launch_bounds__(256) void proj_prep(
    const float* __restrict__ wstep, const float* __restrict__ wgatew,
    u16* __restrict__ Bt16)
{
  int id = blockIdx.x*256 + threadIdx.x;   // 0..16383
  int n = id>>10, k = id&1023;
  float v = (n < 8) ? wstep[k*8 + n] : wgatew[k*8 + (n-8)];
  Bt16[id] = f2b(v);
}

// ---------------- norms: streaming rmsnorm, one wave per token ----------------

__global__ __launch_bounds__(256) void norms_only(
    const float* __restrict__ seq, const float* __restrict__ gs,
    const float* __restrict__ gr, u16* __restrict__ ss, u16* __restrict__ sr)
{
  int w = threadIdx.x>>6, lane = threadIdx.x&63;
  int t = blockIdx.x*4 + w;
  const float* row = seq + (size_t)t*1024;
  f32x4 x[4];
  float ssq = 0.f;
#pragma unroll
  for (int j=0;j<4;++j) {
    x[j] = *(const f32x4*)&row[j*256 + lane*4];
    ssq += x[j][0]*x[j][0] + x[j][1]*x[j][1] + x[j][2]*x[j][2] + x[j][3]*x[j][3];
  }
  for (int m=32;m;m>>=1) ssq += __shfl_xor(ssq, m);
  float inv = rsqrtf(ssq*(1.f/1024.f) + 1e-6f);
#pragma unroll
  for (int j=0;j<4;++j) {
    int d = j*256 + lane*4;
    f32x4 g4 = *(const f32x4*)&gs[d];
    f32x4 r4 = *(const f32x4*)&gr[d];
    u32x2 ps, pr;
    ps[0] = pk2(x[j][0]*inv*g4[0], x[j][1]*inv*g4[1]);
    ps[1] = pk2(x[j][2]*inv*g4[2], x[j][3]*inv*g4[3]);
    pr[0] = pk2(x[j][0]*inv*r4[0], x[j][1]*inv*r4[1]);
    pr[1] = pk2(x[j][2]*inv*r4[2], x[j][3]*inv*r4[3]);
    *(u32x2*)&ss[(size_t)t*1024 + d] = ps;
    *(u32x2*)&sr[(size_t)t*1024 + d] = pr;
  }
}

// ---------------- proj: lr/gate via MFMA skinny GEMM ----------------

__global__ __launch_bounds__(64) void proj_kernel(
    const u16* __restrict__ ss, const u16* __restrict__ sr,
    const u16* __restrict__ Bt16, float* __restrict__ lr,
    float* __restrict__ gate)
{
  int lane = threadIdx.x;
  int l15 = lane&15, l4 = lane>>4;
  size_t t0 = (size_t)blockIdx.x*16;
  f32x4 acc1 = {}, acc2 = {};
#pragma unroll 8
  for (int ks=0; ks<32; ++ks) {
    int kof = ks*32 + l4*8;
    short8 bf = *(const short8*)&Bt16[l15*1024 + kof];
    short8 as = *(const short8*)&ss[(t0+l15)*1024 + kof];
    short8 ar = *(const short8*)&sr[(t0+l15)*1024 + kof];
    acc1 = __builtin_amdgcn_mfma_f32_16x16x32_bf16(as, bf, acc1, 0,0,0);
    acc2 = __builtin_amdgcn_mfma_f32_16x16x32_bf16(ar, bf, acc2, 0,0,0);
  }
  int col = l15;
#pragma unroll
  for (int j=0;j<4;++j) {
    int t = (int)t0 + l4*4 + j;
    int b = t>>12, pos = t&4095;
    if (col < 8) lr[((size_t)(b*8+col))*4096 + pos] = sigm(acc1[j])*0.01f;
    else gate[((size_t)(b*8+(col-8)))*4096 + pos] = sigm(acc2[j]);
  }
}

// ---------------- per-chunk gates from cmean (vectorized loads) ----------------

__global__ __launch_bounds__(256) void chunkgates_kernel(
    const u16* __restrict__ ss, const float* __restrict__ wmom,
    const float* __restrict__ wdec, float* __restrict__ mg,
    float* __restrict__ d1m)
{
  int bc = blockIdx.x; int b = bc>>6, ch = bc&63;
  size_t t0 = (size_t)(b*4096 + ch*64)*1024;
  int tid = threadIdx.x;
  int d0 = tid*4;                       // 4 contiguous cols per thread
  float cm[4]; cm[0]=cm[1]=cm[2]=cm[3]=0.f;
  for (int tok=0; tok<64; ++tok) {
    u32x2 v2 = *(const u32x2*)&ss[t0 + (size_t)tok*1024 + d0];
    cm[0] += b2f((u16)(v2[0] & 0xffffu));
    cm[1] += b2f((u16)(v2[0] >> 16));
    cm[2] += b2f((u16)(v2[1] & 0xffffu));
    cm[3] += b2f((u16)(v2[1] >> 16));
  }
  float pm[8], pd[8];
#pragma unroll
  for (int h=0;h<8;++h){ pm[h]=0.f; pd[h]=0.f; }
#pragma unroll
  for (int i=0;i<4;++i) {
    float v = cm[i]*(1.f/64.f);
    int d = d0 + i;
#pragma unroll
    for (int h=0;h<8;++h){ pm[h]+=v*wmom[d*8+h]; pd[h]+=v*wdec[d*8+h]; }
  }
#pragma unroll
  for (int h=0;h<8;++h)
    for (int m=32;m;m>>=1){ pm[h] += __shfl_xor(pm[h],m); pd[h] += __shfl_xor(pd[h],m); }
  __shared__ float r2[4][16];
  int wv = tid>>6;
  if ((tid&63)==0) {
#pragma unroll
    for (int h=0;h<8;++h){ r2[wv][h]=pm[h]; r2[wv][8+h]=pd[h]; }
  }
  __syncthreads();
  if (tid < 16) {
    float s = r2[0][tid]+r2[1][tid]+r2[2][tid]+r2[3][tid];
    if (tid<8) mg[(b*8+tid)*64 + ch] = sigm(s);
    else d1m[(b*8+(tid-8))*64 + ch] = 1.f - sigm(s);
  }
}

// ---------------- generic bf16 GEMM: C = A(MxK) @ Bt(NxK)^T ----------------
// 512 threads, 8 waves (2M x 4N), wave tile 64x32, double-buffered LDS (64KB),
// issue-early staging: STAGE(next) -> ds_read+MFMA(cur) -> vmcnt(0)+barrier.
// kvT != nullptr (kv GEMM only): keys half (col<1024) additionally stored as
// per-chunk transposed tiles kT[chunk][d:128][r:64] (XOR-swizzled).

__global__ __launch_bounds__(512, 4) void gemm_bt(
    const u16* __restrict__ A, const u16* __restrict__ Bt,
    void* __restrict__ C, int M, int N, int K, int out_f32,
    u16* __restrict__ kvT)
{
  __shared__ __align__(16) u16 As[2][128*64];
  __shared__ __align__(16) u16 Bs[2][128*64];
  int tid = threadIdx.x;
  int w = tid>>6, lane = tid&63;
  int wr = w>>2, wc = w&3;
  int l15 = lane&15, l4 = lane>>4;
  int rl = lane>>3;
  int cg = (lane&7) ^ rl;
  int nwg = gridDim.x*gridDim.y;
  int wg  = blockIdx.y*gridDim.x + blockIdx.x;
  int cpx = nwg >> 3;
  int swz = (wg & 7)*cpx + (wg >> 3);
  int bx = swz % gridDim.x, by = swz / gridDim.x;
  int brow = by*128, bcol = bx*128;
  f32x4 acc[4][2] = {};

  auto STAGE = [&](int buf, int kt) {
#pragma unroll
    for (int i=0;i<2;++i) {
      int row = w*16 + i*8;
      gl16(&A [(size_t)(brow+row+rl)*K + kt + cg*8], &As[buf][row*64]);
      gl16(&Bt[(size_t)(bcol+row+rl)*K + kt + cg*8], &Bs[buf][row*64]);
    }
  };

  int nk = K >> 6;
  STAGE(0, 0);
  asm volatile("s_waitcnt vmcnt(0)");
  __syncthreads();
  for (int t=0; t<nk; ++t) {
    int cur = t & 1;
    if (t+1 < nk) STAGE(cur^1, (t+1)*64);
#pragma unroll
    for (int ks=0; ks<2; ++ks) {
      short8 af[4], bf[2];
#pragma unroll
      for (int m=0;m<4;++m) {
        int row = wr*64 + m*16 + l15;
        int g = ks*4 + l4;
        af[m] = *(const short8*)&As[cur][row*64 + ((g ^ (row&7))<<3)];
      }
#pragma unroll
      for (int n=0;n<2;++n) {
        int row = wc*32 + n*16 + l15;
        int g = ks*4 + l4;
        bf[n] = *(const short8*)&Bs[cur][row*64 + ((g ^ (row&7))<<3)];
      }
#pragma unroll
      for (int m=0;m<4;++m)
#pragma unroll
        for (int n=0;n<2;++n)
          acc[m][n] = __builtin_amdgcn_mfma_f32_16x16x32_bf16(af[m], bf[n], acc[m][n], 0,0,0);
    }
    asm volatile("s_waitcnt vmcnt(0)");
    __syncthreads();
  }
#pragma unroll
  for (int m=0;m<4;++m) {
#pragma unroll
    for (int n=0;n<2;++n) {
      int col = bcol + wc*32 + n*16 + l15;
#pragma unroll
      for (int j=0;j<4;++j) {
        int row = brow + wr*64 + m*16 + l4*4 + j;
        if (out_f32) ((float*)C)[(size_t)row*N + col] = acc[m][n][j];
        else ((u16*)C)[(size_t)row*N + col] = f2b(acc[m][n][j]);
      }
    }
  }
  if (kvT) {
#pragma unroll
    for (int m=0;m<4;++m) {
#pragma unroll
      for (int n=0;n<2;++n) {
        int col = bcol + wc*32 + n*16 + l15;
        if (col < 1024) {
          int row0 = brow + wr*64 + m*16 + l4*4;
          int d = col & 127;
          int chunk = ((row0>>12)*8 + (col>>7))*64 + ((row0&4095)>>6);
          int rr = row0 & 63;
          u32x2 p; p[0] = pk2(acc[m][n][0], acc[m][n][1]);
                   p[1] = pk2(acc[m][n][2], acc[m][n][3]);
          *(u32x2*)&kvT[(size_t)chunk*8192 + taddr(d, rr)] = p;
        }
      }
    }
  }
}

// ---------------- mlp_fwd ----------------

__global__ __launch_bounds__(512) void mlp_fwd(
    const u16* __restrict__ kvout, const float* __restrict__ lr,
    const u16* __restrict__ w0Ts, const u16* __restrict__ w1Ts,
    const u16* __restrict__ w1bs,
    u16* __restrict__ aTg, u16* __restrict__ dpTg, u16* __restrict__ dxTg)
{
  __shared__ __align__(16) u16 W0L[16384];
  __shared__ __align__(16) u16 W1L[16384];
  __shared__ __align__(16) u16 WBL[16384];
  __shared__ __align__(16) u16 abuf[16384];
  int tid = threadIdx.x;
  int w = tid>>6, lane = tid&63;
  int l15 = lane&15, l4 = lane>>4;
#pragma unroll
  for (int it=0; it<4; ++it) {
    int wb = it*512 + w*64;
    gl16((const short8*)w0Ts + wb + lane, (short8*)W0L + wb);
    gl16((const short8*)w1Ts + wb + lane, (short8*)W1L + wb);
    gl16((const short8*)w1bs + wb + lane, (short8*)WBL + wb);
  }
  __syncthreads();
  u16* ab = abuf + w*2048;
  int r0 = l4*4;
  int q = w&3, half = w>>2;
  int rb = q*16;
#pragma unroll
  for (int it2=0; it2<2; ++it2) {
    int cidx = blockIdx.x*4 + it2*2 + half;
    int bh = cidx>>6, ch = cidx&63;
    int b = bh>>3, hh = bh&7;
    size_t t0 = (size_t)(b*4096 + ch*64 + rb);
    size_t tout = (size_t)cidx*8192;
    f32x4 lrv = *(const f32x4*)&lr[(size_t)bh*4096 + ch*64 + rb + r0];

    f32x4 x1[8] = {};
#pragma unroll
    for (int ks=0; ks<4; ++ks) {
      short8 af = *(const short8*)&kvout[(t0 + l15)*2048 + hh*128 + ks*32 + l4*8];
#pragma unroll
      for (int n=0;n<8;++n) {
        short8 bf = frag_row_lds128(W0L, n*16+l15, ks, l4);
        x1[n] = __builtin_amdgcn_mfma_f32_16x16x32_bf16(af, bf, x1[n], 0,0,0);
      }
    }
#pragma unroll
    for (int n=0;n<8;++n) {
      int c = n*16 + l15;
      float av[4];
#pragma unroll
      for (int j=0;j<4;++j){ float xv = x1[n][j]; av[j] = xv*sigm(xv); }
      ab[sidx(r0+0,c)] = f2b(av[0]);
      ab[sidx(r0+1,c)] = f2b(av[1]);
      ab[sidx(r0+2,c)] = f2b(av[2]);
      ab[sidx(r0+3,c)] = f2b(av[3]);
      u32x2 p; p[0] = pk2(av[0],av[1]); p[1] = pk2(av[2],av[3]);
      *(u32x2*)&aTg[tout + taddr(c, rb + r0)] = p;
    }
    f32x4 pr[8] = {};
#pragma unroll
    for (int ks=0; ks<4; ++ks) {
      short8 af = frag_row_lds128(ab, l15, ks, l4);
#pragma unroll
      for (int n=0;n<8;++n) {
        short8 bf = frag_row_lds128(W1L, n*16+l15, ks, l4);
        pr[n] = __builtin_amdgcn_mfma_f32_16x16x32_bf16(af, bf, pr[n], 0,0,0);
      }
    }
#pragma unroll
    for (int n=0;n<8;++n) {
      int c = n*16 + l15;
      float dv[4];
#pragma unroll
      for (int j=0;j<4;++j) {
        float vv = b2f(kvout[(t0+r0+j)*2048 + 1024 + hh*128 + c]);
        dv[j] = 0.015625f * lrv[j] * (pr[n][j] - vv);
      }
      ab[sidx(r0+0,c)] = f2b(dv[0]);
      ab[sidx(r0+1,c)] = f2b(dv[1]);
      ab[sidx(r0+2,c)] = f2b(dv[2]);
      ab[sidx(r0+3,c)] = f2b(dv[3]);
      u32x2 p; p[0] = pk2(dv[0],dv[1]); p[1] = pk2(dv[2],dv[3]);
      *(u32x2*)&dpTg[tout + taddr(c, rb + r0)] = p;
    }
    f32x4 da[8] = {};
#pragma unroll
    for (int ks=0; ks<4; ++ks) {
      short8 af = frag_row_lds128(ab, l15, ks, l4);
#pragma unroll
      for (int n=0;n<8;++n) {
        short8 bf = frag_row_lds128(WBL, n*16+l15, ks, l4);
        da[n] = __builtin_amdgcn_mfma_f32_16x16x32_bf16(af, bf, da[n], 0,0,0);
      }
    }
#pragma unroll
    for (int n=0;n<8;++n) {
      int c = n*16 + l15;
      float d[4];
#pragma unroll
      for (int j=0;j<4;++j) {
        float xv = x1[n][j];
        float sg = sigm(xv);
        d[j] = da[n][j]*(sg*(1.f + xv*(1.f - sg)));
      }
      u32x2 p; p[0] = pk2(d[0],d[1]); p[1] = pk2(d[2],d[3]);
      *(u32x2*)&dxTg[tout + taddr(c, rb + r0)] = p;
    }
  }
}

// ---------------- grad_op ----------------

__global__ __launch_bounds__(256) void grad_op(
    const u16* __restrict__ dpT, const u16* __restrict__ aT,
    const u16* __restrict__ dxT, const u16* __restrict__ kT,
    u16* __restrict__ S)
{
  __shared__ __align__(16) u16 lds[16384];
  int bid = blockIdx.x;
  int op = bid >> 10;
  int sub = bid & 1023, bh = sub>>6, ch = sub&63;
  size_t tin = (size_t)sub*8192;
  const u16* Ain = op ? (dxT + tin) : (dpT + tin);
  const u16* Bin = op ? (kT  + tin) : (aT  + tin);
  int tid = threadIdx.x;
  int w = tid>>6, lane = tid&63;
  int l15 = lane&15, l4 = lane>>4;

#pragma unroll
  for (int it=0; it<4; ++it) {
    int wb = it*256 + w*64;
    gl16((const short8*)Ain + wb + lane, (short8*)lds + wb);
    gl16((const short8*)Bin + wb + lane, (short8*)(lds+8192) + wb);
  }
  __syncthreads();

  f32x4 g[2][8] = {};
#pragma unroll
  for (int ks=0; ks<2; ++ks) {
    short8 af[2];
#pragma unroll
    for (int mi=0; mi<2; ++mi)
      af[mi] = frag_tile(lds, w*32 + mi*16 + l15, ks, l4);
#pragma unroll
    for (int n=0;n<8;++n) {
      short8 bf = frag_tile(lds+8192, n*16 + l15, ks, l4);
#pragma unroll
      for (int mi=0;mi<2;++mi)
        g[mi][n] = __builtin_amdgcn_mfma_f32_16x16x32_bf16(af[mi], bf, g[mi][n], 0,0,0);
    }
  }
  __syncthreads();

#pragma unroll
  for (int mi=0;mi<2;++mi)
#pragma unroll
    for (int n=0;n<8;++n)
#pragma unroll
      for (int j=0;j<4;++j) {
        int m = w*32 + mi*16 + l4*4 + j, c = n*16 + l15;
        lds[sidx(m,c)] = f2b(-g[mi][n][j]);
      }
  __syncthreads();

  u16* Sout = S + ((size_t)((op ? bh : 16+bh))*64 + ch)*16384;
#pragma unroll
  for (int it=0; it<8; ++it)
    ((short8*)Sout)[it*256+tid] = ((const short8*)lds)[it*256+tid];
}

// ---- scan: double linear recurrence, 2 elements/thread (u32 packed) ----

__global__ __launch_bounds__(256) void scan_kernel(
    u16* __restrict__ S, const float* __restrict__ mg, const float* __restrict__ d1m,
    const u16* __restrict__ w0Ts, const u16* __restrict__ w1Ts)
{
  int bidx = blockIdx.x;              // mbh*32 + eblk
  int eblk = bidx & 31;
  int mbh = bidx >> 5;                // 0..31 (0..15 = S0/w0, 16..31 = S1/w1)
  int bh = mbh & 15;
  int e = (eblk*256 + threadIdx.x)*2;
  uint32_t* base = (uint32_t*)(S + (size_t)mbh*64*16384 + e);
  const u16* wsrc = (mbh < 16) ? w0Ts : w1Ts;
  uint32_t wp = *(const uint32_t*)&wsrc[e];
  float wv0 = b2f((u16)(wp & 0xffffu)), wv1 = b2f((u16)(wp >> 16));
  const float* g1 = mg + bh*64;
  const float* g2 = d1m + bh*64;
  float mom0=0.f, upd0=0.f, mom1=0.f, upd1=0.f;
  for (int c2=0; c2<64; ++c2) {
    uint32_t s2 = base[(size_t)c2*8192];
    float s0 = b2f((u16)(s2 & 0xffffu)), s1 = b2f((u16)(s2 >> 16));
    float gg1 = g1[c2], gg2 = g2[c2];
    mom0 = gg1*mom0 + s0; upd0 = gg2*upd0 + mom0;
    mom1 = gg1*mom1 + s1; upd1 = gg2*upd1 + mom1;
    base[(size_t)c2*8192] = pk2(wv0 + upd0, wv1 + upd1);
  }
}

// ---------------- retrieval ----------------

__global__ __launch_bounds__(256) void retrieve_kernel(
    const u16* __restrict__ qn, const u16* __restrict__ W,
    const float* __restrict__ gamma, const float* __restrict__ gate,
    u16* __restrict__ vals)
{
  __shared__ __align__(16) u16 W0s[16384];
  __shared__ __align__(16) u16 W1s[16384];
  __shared__ __align__(16) u16 QA[8192];
  int bid = blockIdx.x;
  int bh = bid>>6, ch = bid&63;
  int b = bh>>3, h = bh&7;
  int tid = threadIdx.x;
  int w = tid>>6, lane = tid&63;
  int l15 = lane&15, l4 = lane>>4;
  const u16* W0g = W + ((size_t)bh*64 + ch)*16384;
  const u16* W1g = W + ((size_t)(16+bh)*64 + ch)*16384;
#pragma unroll
  for (int it=0; it<8; ++it) {
    int wb = it*256 + w*64;
    gl16((const short8*)W0g + wb + lane, (short8*)W0s + wb);
    gl16((const short8*)W1g + wb + lane, (short8*)W1s + wb);
  }
  u16* qa = QA + w*2048;
#pragma unroll
  for (int it=0; it<4; ++it) {
    int task = it*64 + lane;
    int rloc = task>>4, g = task&15;
    int posn = ch*64 + w*16 + rloc + 63;
    short8 v;
    if (posn < 4096) v = *(const short8*)&qn[((size_t)(b*4096+posn))*1024 + h*128 + g*8];
    else {
#pragma unroll
      for (int i=0;i<8;++i) v[i]=0;
    }
    *(short8*)&qa[rloc*128 + ((g ^ (rloc&7))<<3)] = v;
  }
  __syncthreads();
  f32x4 xx[8] = {};
#pragma unroll
  for (int ks=0; ks<4; ++ks) {
    short8 af = frag_row_lds128(qa, l15, ks, l4);
#pragma unroll
    for (int n=0;n<8;++n) {
      short8 bf = frag_row_lds128(W0s, n*16+l15, ks, l4);
      xx[n] = __builtin_amdgcn_mfma_f32_16x16x32_bf16(af, bf, xx[n], 0,0,0);
    }
  }
  int r0 = l4*4;
#pragma unroll
  for (int n=0;n<8;++n) {
    int c = n*16 + l15;
#pragma unroll
    for (int j=0;j<4;++j) {
      float xv = xx[n][j];
      qa[sidx(r0+j,c)] = f2b(xv * sigm(xv));
    }
  }
  f32x4 vv[8] = {};
#pragma unroll
  for (int ks=0; ks<4; ++ks) {
    short8 af = frag_row_lds128(qa, l15, ks, l4);
#pragma unroll
    for (int n=0;n<8;++n) {
      short8 bf = frag_row_lds128(W1s, n*16+l15, ks, l4);
      vv[n] = __builtin_amdgcn_mfma_f32_16x16x32_bf16(af, bf, vv[n], 0,0,0);
    }
  }
#pragma unroll
  for (int j=0;j<4;++j) {
    float ssq = 0.f;
#pragma unroll
    for (int n=0;n<8;++n) ssq += vv[n][j]*vv[n][j];
    ssq += __shfl_xor(ssq,1); ssq += __shfl_xor(ssq,2);
    ssq += __shfl_xor(ssq,4); ssq += __shfl_xor(ssq,8);
    float rms = rsqrtf(ssq*(1.f/128.f) + 1e-6f);
    int posn = ch*64 + w*16 + r0 + j + 63;
    if (posn < 4096) {
      float gt = gate[(size_t)bh*4096 + posn];
      size_t orow = ((size_t)(b*4096+posn))*1024 + h*128;
#pragma unroll
      for (int n=0;n<8;++n) {
        int c = n*16 + l15;
        vals[orow + c] = f2b(vv[n][j]*rms*(1.f + gamma[h*128+c])*gt);
      }
    }
  }
}

extern "C" void kernel_launch(void* const* d_in, const int* in_sizes, int n_in,
                              void* d_out, int out_size, void* d_ws, size_t ws_size,
                              hipStream_t stream) {
  const float* seq    = (const float*)d_in[0];
  const float* gstore = (const float*)d_in[1];
  const float* gret   = (const float*)d_in[2];
  const float* wkv    = (const float*)d_in[3];
  const float* wq     = (const float*)d_in[4];
  const float* wstep  = (const float*)d_in[5];
  const float* wmom   = (const float*)d_in[6];
  const float* wdec   = (const float*)d_in[7];
  const float* wgatew = (const float*)d_in[8];
  const float* wcomb  = (const float*)d_in[9];
  const float* gamma  = (const float*)d_in[10];
  const float* w0f    = (const float*)d_in[11];
  const float* w1f    = (const float*)d_in[12];
  float* out = (float*)d_out;
  (void)in_sizes; (void)n_in; (void)out_size; (void)ws_size;

  char* p = (char*)d_ws;
  size_t off = 0;
  auto alloc = [&](size_t bytes) -> void* {
    void* r = p + off; off += (bytes + 255) & ~(size_t)255; return r;
  };
  u16* wkvT   = (u16*)alloc((size_t)2048*1024*2);
  u16* wqT    = (u16*)alloc((size_t)1024*1024*2);
  u16* wcombT = (u16*)alloc((size_t)1024*1024*2);
  u16* w0Ts   = (u16*)alloc(16384*2);
  u16* w1Ts   = (u16*)alloc(16384*2);
  u16* w1bs   = (u16*)alloc(16384*2);
  u16* Bt16   = (u16*)alloc(16384*2);
  u16* ss     = (u16*)alloc((size_t)NTOK*1024*2);
  u16* sr     = (u16*)alloc((size_t)NTOK*1024*2);
  u16* kvout  = (u16*)alloc((size_t)NTOK*2048*2);
  u16* qn     = (u16*)alloc((size_t)NTOK*1024*2);
  u16* vals   = (u16*)alloc((size_t)NTOK*1024*2);
  float* lr   = (float*)alloc((size_t)16*4096*4);
  float* gate = (float*)alloc((size_t)16*4096*4);
  float* mg   = (float*)alloc(1024*4);
  float* d1m  = (float*)alloc(1024*4);
  u16* S      = (u16*)alloc((size_t)32*64*16384*2);
  u16* kTg    = (u16*)alloc((size_t)1024*8192*2);
  u16* aTg    = (u16*)alloc((size_t)1024*8192*2);
  u16* dpTg   = (u16*)alloc((size_t)1024*8192*2);
  u16* dxTg   = (u16*)alloc((size_t)1024*8192*2);

  transpose_bf16<<<dim3(512),dim3(256),0,stream>>>(wkv, wkvT, 1024, 2048);
  transpose_bf16<<<dim3(256),dim3(256),0,stream>>>(wq, wqT, 1024, 1024);
  transpose_bf16<<<dim3(256),dim3(256),0,stream>>>(wcomb, wcombT, 1024, 1024);
  smallprep<<<dim3(64),dim3(256),0,stream>>>(w0f, w1f, w0Ts, w1Ts, w1bs);
  proj_prep<<<dim3(64),dim3(256),0,stream>>>(wstep, wgatew, Bt16);
  norms_only<<<dim3(2048),dim3(256),0,stream>>>(seq, gstore, gret, ss, sr);
  proj_kernel<<<dim3(512),dim3(64),0,stream>>>(ss, sr, Bt16, lr, gate);
  chunkgates_kernel<<<dim3(128),dim3(256),0,stream>>>(ss, wmom, wdec, mg, d1m);
  gemm_bt<<<dim3(16,64),dim3(512),0,stream>>>(ss, wkvT, kvout, 8192, 2048, 1024, 0, kTg);
  gemm_bt<<<dim3(8,64),dim3(512),0,stream>>>(sr, wqT, qn, 8192, 1024, 1024, 0, nullptr);
  mlp_fwd<<<dim3(256),dim3(512),0,stream>>>(kvout, lr, w0Ts, w1Ts, w1bs, aTg, dpTg, dxTg);
  grad_op<<<dim3(2048),dim3(256),0,stream>>>(dpTg, aTg, dxTg, kTg, S);
  scan_kernel<<<dim3(1024),dim3(256),0,stream>>>(S, mg, d1m, w0Ts, w1Ts);
  hipMemsetAsync(vals, 0, 63*1024*2, stream);
  hipMemsetAsync(vals + (size_t)4096*1024, 0, 63*1024*2, stream);
  retrieve_kernel<<<dim3(1024),dim3(256),0,stream>>>(qn, S, gamma, gate, vals);
  gemm_bt<<<dim3(8,64),dim3(512),0,stream>>>(vals, wcombT, out, 8192, 1024, 1024, 1, nullptr);
}

// Round 16
// 226.780 us; speedup vs baseline: 1.3576x; 1.0559x over previous
//
#include <hip/hip_runtime.h>
#include <stdint.h>

// NeuralMemory (Titans-style) for MI355X / gfx950.
//  prep_all (weights transpose/pack, 1 dispatch) -> norms_only + proj ->
//  kv GEMM (+kT epilogue) / q GEMM -> mlp_fwd (weights in LDS) ->
//  grad_op (outer products -> S, swizzled) -> scan (folds w+U -> W, x2 vec) ->
//  retrieve (W staged in LDS; ch==0 blocks zero the pad rows) -> combine GEMM.
//  GEMM: 128x128 tile, 2-buffer LDS, issue-early global_load_lds, 2 blocks/CU.
//  [History: r11 3-buf regressed; r13 counted-vmcnt neutral; r14 fusion
//   regressed (2B scatter stores). Hot kernels = r12/r15 measured-best.]

#define SEQ 4096
#define NTOK 8192

typedef unsigned short u16;
typedef __attribute__((ext_vector_type(8))) short short8;
typedef __attribute__((ext_vector_type(4))) float f32x4;
typedef __attribute__((ext_vector_type(2))) unsigned int u32x2;

__device__ __forceinline__ u16 f2b(float f) {
  union { float f; uint32_t u; } c; c.f = f;
  uint32_t u = c.u;
  uint32_t r = (u + 0x7fffu + ((u >> 16) & 1u)) >> 16;
  return (u16)r;
}
__device__ __forceinline__ float b2f(u16 h) {
  union { uint32_t u; float f; } c; c.u = ((uint32_t)h) << 16;
  return c.f;
}
__device__ __forceinline__ float sigm(float x) { return 1.f / (1.f + __expf(-x)); }
__device__ __forceinline__ uint32_t pk2(float a, float b) {
  return (uint32_t)f2b(a) | ((uint32_t)f2b(b) << 16);
}
__device__ __forceinline__ void gl16(const void* g, void* l) {
  __builtin_amdgcn_global_load_lds(
      (const __attribute__((address_space(1))) unsigned int*)g,
      (__attribute__((address_space(3))) unsigned int*)l, 16, 0, 0);
}

__device__ __forceinline__ int sidx(int r, int c) {
  return r*128 + ((((c>>3) ^ (r&7))<<3) | (c&7));
}
__device__ __forceinline__ short8 frag_row_lds128(const u16* buf, int row, int ks, int l4) {
  int g = ks*4 + l4;
  return *(const short8*)&buf[row*128 + ((g ^ (row&7))<<3)];
}
__device__ __forceinline__ short8 frag_tile(const u16* t, int row, int ks, int l4) {
  return *(const short8*)&t[row*64 + (((ks*4 + l4) ^ (row&7))<<3)];
}
__device__ __forceinline__ int taddr(int c, int r0) {
  return c*64 + (r0 ^ ((c&7)<<3));
}

// ---------------- prep_all: all weight prep in one dispatch ----------------
// blocks 0..511   : transpose wkv   (1024x2048 -> wkvT)
// blocks 512..767 : transpose wq    (1024x1024 -> wqT)
// blocks 768..1023: transpose wcomb (1024x1024 -> wcombT)
// blocks 1024..1087: smallprep (w0/w1 -> w0Ts/w1Ts/w1bs, swizzled)
// blocks 1088..1151: proj_prep (wstep/wgate -> Bt16)

__global__ __launch_bounds__(256) void prep_all(
    const float* __restrict__ wkv, const float* __restrict__ wq,
    const float* __restrict__ wcomb, const float* __restrict__ w0,
    const float* __restrict__ w1, const float* __restrict__ wstep,
    const float* __restrict__ wgatew,
    u16* __restrict__ wkvT, u16* __restrict__ wqT, u16* __restrict__ wcombT,
    u16* __restrict__ w0Ts, u16* __restrict__ w1Ts, u16* __restrict__ w1bs,
    u16* __restrict__ Bt16)
{
  __shared__ u16 tile[64*66];
  int bid = blockIdx.x;
  int tid = threadIdx.x;
  if (bid < 1024) {
    const float* src; u16* dst; int C; int bidx;
    if (bid < 512)      { src = wkv;   dst = wkvT;   C = 2048; bidx = bid; }
    else if (bid < 768) { src = wq;    dst = wqT;    C = 1024; bidx = bid - 512; }
    else                { src = wcomb; dst = wcombT; C = 1024; bidx = bid - 768; }
    const int R = 1024;
    int tiles_x = C >> 6;
    int tx = bidx % tiles_x, ty = bidx / tiles_x;
    int c0 = tx*64, r0 = ty*64;
#pragma unroll
    for (int it=0; it<16; ++it) {
      int idx = it*256 + tid;
      int rr = idx>>6, cc = idx&63;
      tile[cc*66 + rr] = f2b(src[(size_t)(r0+rr)*C + c0+cc]);
    }
    __syncthreads();
#pragma unroll
    for (int it=0; it<16; ++it) {
      int idx = it*256 + tid;
      int rr = idx>>6, cc = idx&63;
      dst[(size_t)(c0+rr)*R + r0+cc] = tile[rr*66 + cc];
    }
  } else if (bid < 1088) {
    int id = (bid-1024)*256 + tid;     // 0..16383
    int i = id>>7, j = id&127;
    float a = w0[id], b = w1[id];
    w0Ts[sidx(j,i)] = f2b(a);
    w1Ts[sidx(j,i)] = f2b(b);
    w1bs[sidx(i,j)] = f2b(b);
  } else {
    int id = (bid-1088)*256 + tid;     // 0..16383
    int n = id>>10, k = id&1023;
    float v = (n < 8) ? wstep[k*8 + n] : wgatew[k*8 + (n-8)];
    Bt16[id] = f2b(v);
  }
}

// ---------------- norms: streaming rmsnorm, one wave per token ----------------

__global__ __launch_bounds__(256) void norms_only(
    const float* __restrict__ seq, const float* __restrict__ gs,
    const float* __restrict__ gr, u16* __restrict__ ss, u16* __restrict__ sr)
{
  int w = threadIdx.x>>6, lane = threadIdx.x&63;
  int t = blockIdx.x*4 + w;
  const float* row = seq + (size_t)t*1024;
  f32x4 x[4];
  float ssq = 0.f;
#pragma unroll
  for (int j=0;j<4;++j) {
    x[j] = *(const f32x4*)&row[j*256 + lane*4];
    ssq += x[j][0]*x[j][0] + x[j][1]*x[j][1] + x[j][2]*x[j][2] + x[j][3]*x[j][3];
  }
  for (int m=32;m;m>>=1) ssq += __shfl_xor(ssq, m);
  float inv = rsqrtf(ssq*(1.f/1024.f) + 1e-6f);
#pragma unroll
  for (int j=0;j<4;++j) {
    int d = j*256 + lane*4;
    f32x4 g4 = *(const f32x4*)&gs[d];
    f32x4 r4 = *(const f32x4*)&gr[d];
    u32x2 ps, pr;
    ps[0] = pk2(x[j][0]*inv*g4[0], x[j][1]*inv*g4[1]);
    ps[1] = pk2(x[j][2]*inv*g4[2], x[j][3]*inv*g4[3]);
    pr[0] = pk2(x[j][0]*inv*r4[0], x[j][1]*inv*r4[1]);
    pr[1] = pk2(x[j][2]*inv*r4[2], x[j][3]*inv*r4[3]);
    *(u32x2*)&ss[(size_t)t*1024 + d] = ps;
    *(u32x2*)&sr[(size_t)t*1024 + d] = pr;
  }
}

// ---------------- proj: lr/gate via MFMA skinny GEMM ----------------

__global__ __launch_bounds__(64) void proj_kernel(
    const u16* __restrict__ ss, const u16* __restrict__ sr,
    const u16* __restrict__ Bt16, float* __restrict__ lr,
    float* __restrict__ gate)
{
  int lane = threadIdx.x;
  int l15 = lane&15, l4 = lane>>4;
  size_t t0 = (size_t)blockIdx.x*16;
  f32x4 acc1 = {}, acc2 = {};
#pragma unroll 8
  for (int ks=0; ks<32; ++ks) {
    int kof = ks*32 + l4*8;
    short8 bf = *(const short8*)&Bt16[l15*1024 + kof];
    short8 as = *(const short8*)&ss[(t0+l15)*1024 + kof];
    short8 ar = *(const short8*)&sr[(t0+l15)*1024 + kof];
    acc1 = __builtin_amdgcn_mfma_f32_16x16x32_bf16(as, bf, acc1, 0,0,0);
    acc2 = __builtin_amdgcn_mfma_f32_16x16x32_bf16(ar, bf, acc2, 0,0,0);
  }
  int col = l15;
#pragma unroll
  for (int j=0;j<4;++j) {
    int t = (int)t0 + l4*4 + j;
    int b = t>>12, pos = t&4095;
    if (col < 8) lr[((size_t)(b*8+col))*4096 + pos] = sigm(acc1[j])*0.01f;
    else gate[((size_t)(b*8+(col-8)))*4096 + pos] = sigm(acc2[j]);
  }
}

// ---------------- per-chunk gates from cmean (vectorized loads) ----------------

__global__ __launch_bounds__(256) void chunkgates_kernel(
    const u16* __restrict__ ss, const float* __restrict__ wmom,
    const float* __restrict__ wdec, float* __restrict__ mg,
    float* __restrict__ d1m)
{
  int bc = blockIdx.x; int b = bc>>6, ch = bc&63;
  size_t t0 = (size_t)(b*4096 + ch*64)*1024;
  int tid = threadIdx.x;
  int d0 = tid*4;                       // 4 contiguous cols per thread
  float cm[4]; cm[0]=cm[1]=cm[2]=cm[3]=0.f;
  for (int tok=0; tok<64; ++tok) {
    u32x2 v2 = *(const u32x2*)&ss[t0 + (size_t)tok*1024 + d0];
    cm[0] += b2f((u16)(v2[0] & 0xffffu));
    cm[1] += b2f((u16)(v2[0] >> 16));
    cm[2] += b2f((u16)(v2[1] & 0xffffu));
    cm[3] += b2f((u16)(v2[1] >> 16));
  }
  float pm[8], pd[8];
#pragma unroll
  for (int h=0;h<8;++h){ pm[h]=0.f; pd[h]=0.f; }
#pragma unroll
  for (int i=0;i<4;++i) {
    float v = cm[i]*(1.f/64.f);
    int d = d0 + i;
#pragma unroll
    for (int h=0;h<8;++h){ pm[h]+=v*wmom[d*8+h]; pd[h]+=v*wdec[d*8+h]; }
  }
#pragma unroll
  for (int h=0;h<8;++h)
    for (int m=32;m;m>>=1){ pm[h] += __shfl_xor(pm[h],m); pd[h] += __shfl_xor(pd[h],m); }
  __shared__ float r2[4][16];
  int wv = tid>>6;
  if ((tid&63)==0) {
#pragma unroll
    for (int h=0;h<8;++h){ r2[wv][h]=pm[h]; r2[wv][8+h]=pd[h]; }
  }
  __syncthreads();
  if (tid < 16) {
    float s = r2[0][tid]+r2[1][tid]+r2[2][tid]+r2[3][tid];
    if (tid<8) mg[(b*8+tid)*64 + ch] = sigm(s);
    else d1m[(b*8+(tid-8))*64 + ch] = 1.f - sigm(s);
  }
}

// ---------------- generic bf16 GEMM: C = A(MxK) @ Bt(NxK)^T ----------------
// 512 threads, 8 waves (2M x 4N), wave tile 64x32, double-buffered LDS (64KB),
// issue-early staging: STAGE(next) -> ds_read+MFMA(cur) -> vmcnt(0)+barrier.
// kvT != nullptr (kv GEMM only): keys half (col<1024) additionally stored as
// per-chunk transposed tiles kT[chunk][d:128][r:64] (XOR-swizzled).

__global__ __launch_bounds__(512, 4) void gemm_bt(
    const u16* __restrict__ A, const u16* __restrict__ Bt,
    void* __restrict__ C, int M, int N, int K, int out_f32,
    u16* __restrict__ kvT)
{
  __shared__ __align__(16) u16 As[2][128*64];
  __shared__ __align__(16) u16 Bs[2][128*64];
  int tid = threadIdx.x;
  int w = tid>>6, lane = tid&63;
  int wr = w>>2, wc = w&3;
  int l15 = lane&15, l4 = lane>>4;
  int rl = lane>>3;
  int cg = (lane&7) ^ rl;
  int nwg = gridDim.x*gridDim.y;
  int wg  = blockIdx.y*gridDim.x + blockIdx.x;
  int cpx = nwg >> 3;
  int swz = (wg & 7)*cpx + (wg >> 3);
  int bx = swz % gridDim.x, by = swz / gridDim.x;
  int brow = by*128, bcol = bx*128;
  f32x4 acc[4][2] = {};

  auto STAGE = [&](int buf, int kt) {
#pragma unroll
    for (int i=0;i<2;++i) {
      int row = w*16 + i*8;
      gl16(&A [(size_t)(brow+row+rl)*K + kt + cg*8], &As[buf][row*64]);
      gl16(&Bt[(size_t)(bcol+row+rl)*K + kt + cg*8], &Bs[buf][row*64]);
    }
  };

  int nk = K >> 6;
  STAGE(0, 0);
  asm volatile("s_waitcnt vmcnt(0)");
  __syncthreads();
  for (int t=0; t<nk; ++t) {
    int cur = t & 1;
    if (t+1 < nk) STAGE(cur^1, (t+1)*64);
#pragma unroll
    for (int ks=0; ks<2; ++ks) {
      short8 af[4], bf[2];
#pragma unroll
      for (int m=0;m<4;++m) {
        int row = wr*64 + m*16 + l15;
        int g = ks*4 + l4;
        af[m] = *(const short8*)&As[cur][row*64 + ((g ^ (row&7))<<3)];
      }
#pragma unroll
      for (int n=0;n<2;++n) {
        int row = wc*32 + n*16 + l15;
        int g = ks*4 + l4;
        bf[n] = *(const short8*)&Bs[cur][row*64 + ((g ^ (row&7))<<3)];
      }
#pragma unroll
      for (int m=0;m<4;++m)
#pragma unroll
        for (int n=0;n<2;++n)
          acc[m][n] = __builtin_amdgcn_mfma_f32_16x16x32_bf16(af[m], bf[n], acc[m][n], 0,0,0);
    }
    asm volatile("s_waitcnt vmcnt(0)");
    __syncthreads();
  }
#pragma unroll
  for (int m=0;m<4;++m) {
#pragma unroll
    for (int n=0;n<2;++n) {
      int col = bcol + wc*32 + n*16 + l15;
#pragma unroll
      for (int j=0;j<4;++j) {
        int row = brow + wr*64 + m*16 + l4*4 + j;
        if (out_f32) ((float*)C)[(size_t)row*N + col] = acc[m][n][j];
        else ((u16*)C)[(size_t)row*N + col] = f2b(acc[m][n][j]);
      }
    }
  }
  if (kvT) {
#pragma unroll
    for (int m=0;m<4;++m) {
#pragma unroll
      for (int n=0;n<2;++n) {
        int col = bcol + wc*32 + n*16 + l15;
        if (col < 1024) {
          int row0 = brow + wr*64 + m*16 + l4*4;
          int d = col & 127;
          int chunk = ((row0>>12)*8 + (col>>7))*64 + ((row0&4095)>>6);
          int rr = row0 & 63;
          u32x2 p; p[0] = pk2(acc[m][n][0], acc[m][n][1]);
                   p[1] = pk2(acc[m][n][2], acc[m][n][3]);
          *(u32x2*)&kvT[(size_t)chunk*8192 + taddr(d, rr)] = p;
        }
      }
    }
  }
}

// ---------------- mlp_fwd ----------------

__global__ __launch_bounds__(512) void mlp_fwd(
    const u16* __restrict__ kvout, const float* __restrict__ lr,
    const u16* __restrict__ w0Ts, const u16* __restrict__ w1Ts,
    const u16* __restrict__ w1bs,
    u16* __restrict__ aTg, u16* __restrict__ dpTg, u16* __restrict__ dxTg)
{
  __shared__ __align__(16) u16 W0L[16384];
  __shared__ __align__(16) u16 W1L[16384];
  __shared__ __align__(16) u16 WBL[16384];
  __shared__ __align__(16) u16 abuf[16384];
  int tid = threadIdx.x;
  int w = tid>>6, lane = tid&63;
  int l15 = lane&15, l4 = lane>>4;
#pragma unroll
  for (int it=0; it<4; ++it) {
    int wb = it*512 + w*64;
    gl16((const short8*)w0Ts + wb + lane, (short8*)W0L + wb);
    gl16((const short8*)w1Ts + wb + lane, (short8*)W1L + wb);
    gl16((const short8*)w1bs + wb + lane, (short8*)WBL + wb);
  }
  __syncthreads();
  u16* ab = abuf + w*2048;
  int r0 = l4*4;
  int q = w&3, half = w>>2;
  int rb = q*16;
#pragma unroll
  for (int it2=0; it2<2; ++it2) {
    int cidx = blockIdx.x*4 + it2*2 + half;
    int bh = cidx>>6, ch = cidx&63;
    int b = bh>>3, hh = bh&7;
    size_t t0 = (size_t)(b*4096 + ch*64 + rb);
    size_t tout = (size_t)cidx*8192;
    f32x4 lrv = *(const f32x4*)&lr[(size_t)bh*4096 + ch*64 + rb + r0];

    f32x4 x1[8] = {};
#pragma unroll
    for (int ks=0; ks<4; ++ks) {
      short8 af = *(const short8*)&kvout[(t0 + l15)*2048 + hh*128 + ks*32 + l4*8];
#pragma unroll
      for (int n=0;n<8;++n) {
        short8 bf = frag_row_lds128(W0L, n*16+l15, ks, l4);
        x1[n] = __builtin_amdgcn_mfma_f32_16x16x32_bf16(af, bf, x1[n], 0,0,0);
      }
    }
#pragma unroll
    for (int n=0;n<8;++n) {
      int c = n*16 + l15;
      float av[4];
#pragma unroll
      for (int j=0;j<4;++j){ float xv = x1[n][j]; av[j] = xv*sigm(xv); }
      ab[sidx(r0+0,c)] = f2b(av[0]);
      ab[sidx(r0+1,c)] = f2b(av[1]);
      ab[sidx(r0+2,c)] = f2b(av[2]);
      ab[sidx(r0+3,c)] = f2b(av[3]);
      u32x2 p; p[0] = pk2(av[0],av[1]); p[1] = pk2(av[2],av[3]);
      *(u32x2*)&aTg[tout + taddr(c, rb + r0)] = p;
    }
    f32x4 pr[8] = {};
#pragma unroll
    for (int ks=0; ks<4; ++ks) {
      short8 af = frag_row_lds128(ab, l15, ks, l4);
#pragma unroll
      for (int n=0;n<8;++n) {
        short8 bf = frag_row_lds128(W1L, n*16+l15, ks, l4);
        pr[n] = __builtin_amdgcn_mfma_f32_16x16x32_bf16(af, bf, pr[n], 0,0,0);
      }
    }
#pragma unroll
    for (int n=0;n<8;++n) {
      int c = n*16 + l15;
      float dv[4];
#pragma unroll
      for (int j=0;j<4;++j) {
        float vv = b2f(kvout[(t0+r0+j)*2048 + 1024 + hh*128 + c]);
        dv[j] = 0.015625f * lrv[j] * (pr[n][j] - vv);
      }
      ab[sidx(r0+0,c)] = f2b(dv[0]);
      ab[sidx(r0+1,c)] = f2b(dv[1]);
      ab[sidx(r0+2,c)] = f2b(dv[2]);
      ab[sidx(r0+3,c)] = f2b(dv[3]);
      u32x2 p; p[0] = pk2(dv[0],dv[1]); p[1] = pk2(dv[2],dv[3]);
      *(u32x2*)&dpTg[tout + taddr(c, rb + r0)] = p;
    }
    f32x4 da[8] = {};
#pragma unroll
    for (int ks=0; ks<4; ++ks) {
      short8 af = frag_row_lds128(ab, l15, ks, l4);
#pragma unroll
      for (int n=0;n<8;++n) {
        short8 bf = frag_row_lds128(WBL, n*16+l15, ks, l4);
        da[n] = __builtin_amdgcn_mfma_f32_16x16x32_bf16(af, bf, da[n], 0,0,0);
      }
    }
#pragma unroll
    for (int n=0;n<8;++n) {
      int c = n*16 + l15;
      float d[4];
#pragma unroll
      for (int j=0;j<4;++j) {
        float xv = x1[n][j];
        float sg = sigm(xv);
        d[j] = da[n][j]*(sg*(1.f + xv*(1.f - sg)));
      }
      u32x2 p; p[0] = pk2(d[0],d[1]); p[1] = pk2(d[2],d[3]);
      *(u32x2*)&dxTg[tout + taddr(c, rb + r0)] = p;
    }
  }
}

// ---------------- grad_op ----------------

__global__ __launch_bounds__(256) void grad_op(
    const u16* __restrict__ dpT, const u16* __restrict__ aT,
    const u16* __restrict__ dxT, const u16* __restrict__ kT,
    u16* __restrict__ S)
{
  __shared__ __align__(16) u16 lds[16384];
  int bid = blockIdx.x;
  int op = bid >> 10;
  int sub = bid & 1023, bh = sub>>6, ch = sub&63;
  size_t tin = (size_t)sub*8192;
  const u16* Ain = op ? (dxT + tin) : (dpT + tin);
  const u16* Bin = op ? (kT  + tin) : (aT  + tin);
  int tid = threadIdx.x;
  int w = tid>>6, lane = tid&63;
  int l15 = lane&15, l4 = lane>>4;

#pragma unroll
  for (int it=0; it<4; ++it) {
    int wb = it*256 + w*64;
    gl16((const short8*)Ain + wb + lane, (short8*)lds + wb);
    gl16((const short8*)Bin + wb + lane, (short8*)(lds+8192) + wb);
  }
  __syncthreads();

  f32x4 g[2][8] = {};
#pragma unroll
  for (int ks=0; ks<2; ++ks) {
    short8 af[2];
#pragma unroll
    for (int mi=0; mi<2; ++mi)
      af[mi] = frag_tile(lds, w*32 + mi*16 + l15, ks, l4);
#pragma unroll
    for (int n=0;n<8;++n) {
      short8 bf = frag_tile(lds+8192, n*16 + l15, ks, l4);
#pragma unroll
      for (int mi=0;mi<2;++mi)
        g[mi][n] = __builtin_amdgcn_mfma_f32_16x16x32_bf16(af[mi], bf, g[mi][n], 0,0,0);
    }
  }
  __syncthreads();

#pragma unroll
  for (int mi=0;mi<2;++mi)
#pragma unroll
    for (int n=0;n<8;++n)
#pragma unroll
      for (int j=0;j<4;++j) {
        int m = w*32 + mi*16 + l4*4 + j, c = n*16 + l15;
        lds[sidx(m,c)] = f2b(-g[mi][n][j]);
      }
  __syncthreads();

  u16* Sout = S + ((size_t)((op ? bh : 16+bh))*64 + ch)*16384;
#pragma unroll
  for (int it=0; it<8; ++it)
    ((short8*)Sout)[it*256+tid] = ((const short8*)lds)[it*256+tid];
}

// ---- scan: double linear recurrence, 2 elements/thread (u32 packed) ----

__global__ __launch_bounds__(256) void scan_kernel(
    u16* __restrict__ S, const float* __restrict__ mg, const float* __restrict__ d1m,
    const u16* __restrict__ w0Ts, const u16* __restrict__ w1Ts)
{
  int bidx = blockIdx.x;              // mbh*32 + eblk
  int eblk = bidx & 31;
  int mbh = bidx >> 5;                // 0..31 (0..15 = S0/w0, 16..31 = S1/w1)
  int bh = mbh & 15;
  int e = (eblk*256 + threadIdx.x)*2;
  uint32_t* base = (uint32_t*)(S + (size_t)mbh*64*16384 + e);
  const u16* wsrc = (mbh < 16) ? w0Ts : w1Ts;
  uint32_t wp = *(const uint32_t*)&wsrc[e];
  float wv0 = b2f((u16)(wp & 0xffffu)), wv1 = b2f((u16)(wp >> 16));
  const float* g1 = mg + bh*64;
  const float* g2 = d1m + bh*64;
  float mom0=0.f, upd0=0.f, mom1=0.f, upd1=0.f;
  for (int c2=0; c2<64; ++c2) {
    uint32_t s2 = base[(size_t)c2*8192];
    float s0 = b2f((u16)(s2 & 0xffffu)), s1 = b2f((u16)(s2 >> 16));
    float gg1 = g1[c2], gg2 = g2[c2];
    mom0 = gg1*mom0 + s0; upd0 = gg2*upd0 + mom0;
    mom1 = gg1*mom1 + s1; upd1 = gg2*upd1 + mom1;
    base[(size_t)c2*8192] = pk2(wv0 + upd0, wv1 + upd1);
  }
}

// ---------------- retrieval (ch==0 blocks also zero the pad rows) ----------------

__global__ __launch_bounds__(256) void retrieve_kernel(
    const u16* __restrict__ qn, const u16* __restrict__ W,
    const float* __restrict__ gamma, const float* __restrict__ gate,
    u16* __restrict__ vals)
{
  __shared__ __align__(16) u16 W0s[16384];
  __shared__ __align__(16) u16 W1s[16384];
  __shared__ __align__(16) u16 QA[8192];
  int bid = blockIdx.x;
  int bh = bid>>6, ch = bid&63;
  int b = bh>>3, h = bh&7;
  int tid = threadIdx.x;
  int w = tid>>6, lane = tid&63;
  int l15 = lane&15, l4 = lane>>4;
  const u16* W0g = W + ((size_t)bh*64 + ch)*16384;
  const u16* W1g = W + ((size_t)(16+bh)*64 + ch)*16384;
#pragma unroll
  for (int it=0; it<8; ++it) {
    int wb = it*256 + w*64;
    gl16((const short8*)W0g + wb + lane, (short8*)W0s + wb);
    gl16((const short8*)W1g + wb + lane, (short8*)W1s + wb);
  }
  // pad rows: vals positions 0..62 per batch get no store; ch==0 blocks zero
  // their own (b,h) slice (replaces the two hipMemsetAsync dispatches)
  if (ch == 0) {
    for (int r = w; r < 63; r += 4)
      *(uint32_t*)&vals[((size_t)(b*4096 + r))*1024 + h*128 + lane*2] = 0;
  }
  u16* qa = QA + w*2048;
#pragma unroll
  for (int it=0; it<4; ++it) {
    int task = it*64 + lane;
    int rloc = task>>4, g = task&15;
    int posn = ch*64 + w*16 + rloc + 63;
    short8 v;
    if (posn < 4096) v = *(const short8*)&qn[((size_t)(b*4096+posn))*1024 + h*128 + g*8];
    else {
#pragma unroll
      for (int i=0;i<8;++i) v[i]=0;
    }
    *(short8*)&qa[rloc*128 + ((g ^ (rloc&7))<<3)] = v;
  }
  __syncthreads();
  f32x4 xx[8] = {};
#pragma unroll
  for (int ks=0; ks<4; ++ks) {
    short8 af = frag_row_lds128(qa, l15, ks, l4);
#pragma unroll
    for (int n=0;n<8;++n) {
      short8 bf = frag_row_lds128(W0s, n*16+l15, ks, l4);
      xx[n] = __builtin_amdgcn_mfma_f32_16x16x32_bf16(af, bf, xx[n], 0,0,0);
    }
  }
  int r0 = l4*4;
#pragma unroll
  for (int n=0;n<8;++n) {
    int c = n*16 + l15;
#pragma unroll
    for (int j=0;j<4;++j) {
      float xv = xx[n][j];
      qa[sidx(r0+j,c)] = f2b(xv * sigm(xv));
    }
  }
  f32x4 vv[8] = {};
#pragma unroll
  for (int ks=0; ks<4; ++ks) {
    short8 af = frag_row_lds128(qa, l15, ks, l4);
#pragma unroll
    for (int n=0;n<8;++n) {
      short8 bf = frag_row_lds128(W1s, n*16+l15, ks, l4);
      vv[n] = __builtin_amdgcn_mfma_f32_16x16x32_bf16(af, bf, vv[n], 0,0,0);
    }
  }
#pragma unroll
  for (int j=0;j<4;++j) {
    float ssq = 0.f;
#pragma unroll
    for (int n=0;n<8;++n) ssq += vv[n][j]*vv[n][j];
    ssq += __shfl_xor(ssq,1); ssq += __shfl_xor(ssq,2);
    ssq += __shfl_xor(ssq,4); ssq += __shfl_xor(ssq,8);
    float rms = rsqrtf(ssq*(1.f/128.f) + 1e-6f);
    int posn = ch*64 + w*16 + r0 + j + 63;
    if (posn < 4096) {
      float gt = gate[(size_t)bh*4096 + posn];
      size_t orow = ((size_t)(b*4096+posn))*1024 + h*128;
#pragma unroll
      for (int n=0;n<8;++n) {
        int c = n*16 + l15;
        vals[orow + c] = f2b(vv[n][j]*rms*(1.f + gamma[h*128+c])*gt);
      }
    }
  }
}

extern "C" void kernel_launch(void* const* d_in, const int* in_sizes, int n_in,
                              void* d_out, int out_size, void* d_ws, size_t ws_size,
                              hipStream_t stream) {
  const float* seq    = (const float*)d_in[0];
  const float* gstore = (const float*)d_in[1];
  const float* gret   = (const float*)d_in[2];
  const float* wkv    = (const float*)d_in[3];
  const float* wq     = (const float*)d_in[4];
  const float* wstep  = (const float*)d_in[5];
  const float* wmom   = (const float*)d_in[6];
  const float* wdec   = (const float*)d_in[7];
  const float* wgatew = (const float*)d_in[8];
  const float* wcomb  = (const float*)d_in[9];
  const float* gamma  = (const float*)d_in[10];
  const float* w0f    = (const float*)d_in[11];
  const float* w1f    = (const float*)d_in[12];
  float* out = (float*)d_out;
  (void)in_sizes; (void)n_in; (void)out_size; (void)ws_size;

  char* p = (char*)d_ws;
  size_t off = 0;
  auto alloc = [&](size_t bytes) -> void* {
    void* r = p + off; off += (bytes + 255) & ~(size_t)255; return r;
  };
  u16* wkvT   = (u16*)alloc((size_t)2048*1024*2);
  u16* wqT    = (u16*)alloc((size_t)1024*1024*2);
  u16* wcombT = (u16*)alloc((size_t)1024*1024*2);
  u16* w0Ts   = (u16*)alloc(16384*2);
  u16* w1Ts   = (u16*)alloc(16384*2);
  u16* w1bs   = (u16*)alloc(16384*2);
  u16* Bt16   = (u16*)alloc(16384*2);
  u16* ss     = (u16*)alloc((size_t)NTOK*1024*2);
  u16* sr     = (u16*)alloc((size_t)NTOK*1024*2);
  u16* kvout  = (u16*)alloc((size_t)NTOK*2048*2);
  u16* qn     = (u16*)alloc((size_t)NTOK*1024*2);
  u16* vals   = (u16*)alloc((size_t)NTOK*1024*2);
  float* lr   = (float*)alloc((size_t)16*4096*4);
  float* gate = (float*)alloc((size_t)16*4096*4);
  float* mg   = (float*)alloc(1024*4);
  float* d1m  = (float*)alloc(1024*4);
  u16* S      = (u16*)alloc((size_t)32*64*16384*2);
  u16* kTg    = (u16*)alloc((size_t)1024*8192*2);
  u16* aTg    = (u16*)alloc((size_t)1024*8192*2);
  u16* dpTg   = (u16*)alloc((size_t)1024*8192*2);
  u16* dxTg   = (u16*)alloc((size_t)1024*8192*2);

  prep_all<<<dim3(1152),dim3(256),0,stream>>>(wkv, wq, wcomb, w0f, w1f, wstep, wgatew,
                                              wkvT, wqT, wcombT, w0Ts, w1Ts, w1bs, Bt16);
  norms_only<<<dim3(2048),dim3(256),0,stream>>>(seq, gstore, gret, ss, sr);
  proj_kernel<<<dim3(512),dim3(64),0,stream>>>(ss, sr, Bt16, lr, gate);
  chunkgates_kernel<<<dim3(128),dim3(256),0,stream>>>(ss, wmom, wdec, mg, d1m);
  gemm_bt<<<dim3(16,64),dim3(512),0,stream>>>(ss, wkvT, kvout, 8192, 2048, 1024, 0, kTg);
  gemm_bt<<<dim3(8,64),dim3(512),0,stream>>>(sr, wqT, qn, 8192, 1024, 1024, 0, nullptr);
  mlp_fwd<<<dim3(256),dim3(512),0,stream>>>(kvout, lr, w0Ts, w1Ts, w1bs, aTg, dpTg, dxTg);
  grad_op<<<dim3(2048),dim3(256),0,stream>>>(dpTg, aTg, dxTg, kTg, S);
  scan_kernel<<<dim3(1024),dim3(256),0,stream>>>(S, mg, d1m, w0Ts, w1Ts);
  retrieve_kernel<<<dim3(1024),dim3(256),0,stream>>>(qn, S, gamma, gate, vals);
  gemm_bt<<<dim3(8,64),dim3(512),0,stream>>>(vals, wcombT, out, 8192, 1024, 1024, 1, nullptr);
}